// Round 2
// baseline (681.615 us; speedup 1.0000x reference)
//
#include <hip/hip_runtime.h>
#include <stdint.h>

#define H_ 16
#define D_ 1024
#define SPLIT_ 4
#define DK_ 64
#define B_ 4
#define SEQ_ 4096
#define L_ 1024

typedef unsigned short ushort_t;
typedef __attribute__((ext_vector_type(8))) short short8;
typedef __attribute__((ext_vector_type(4))) float floatx4;
typedef __attribute__((ext_vector_type(4))) unsigned short ushortx4;

__device__ __forceinline__ ushort_t f2bf(float f) {
  union { float f; unsigned u; } cv; cv.f = f;
  unsigned u = cv.u;
  return (ushort_t)((u + 0x7fffu + ((u >> 16) & 1u)) >> 16);
}

// async 16B global->LDS (dest must be wave-uniform base + lane*16)
__device__ __forceinline__ void gl2lds16(const ushort_t* g, ushort_t* l) {
  __builtin_amdgcn_global_load_lds(
      (const __attribute__((address_space(1))) uint32_t*)g,
      (__attribute__((address_space(3))) uint32_t*)l, 16, 0, 0);
}

// ------------- x: fp32 -> bf16 (contiguous) ---------------------------------
__global__ __launch_bounds__(256) void convert_x(const float* __restrict__ X,
                                                 ushort_t* __restrict__ Y) {
  const int i = blockIdx.x * 256 + threadIdx.x;
  const float4 v = ((const float4*)X)[i];
  ushortx4 o;
  o[0] = f2bf(v.x); o[1] = f2bf(v.y); o[2] = f2bf(v.z); o[3] = f2bf(v.w);
  ((ushortx4*)Y)[i] = o;
}

// ------------- W[s][d][e] fp32 -> Wt[s][e][d] bf16 --------------------------
__global__ __launch_bounds__(256) void wt_convert(const float* __restrict__ W,
                                                  ushort_t* __restrict__ Wt) {
  __shared__ ushort_t tile[32][33];
  const int s = blockIdx.z;
  const float* Ws = W + (size_t)s * D_ * D_;
  ushort_t* Wts = Wt + (size_t)s * D_ * D_;
  const int e0 = blockIdx.x * 32, d0 = blockIdx.y * 32;
  for (int i = threadIdx.y; i < 32; i += 8)
    tile[i][threadIdx.x] = f2bf(Ws[(size_t)(d0 + i) * D_ + e0 + threadIdx.x]);
  __syncthreads();
  for (int i = threadIdx.y; i < 32; i += 8)
    Wts[(size_t)(e0 + i) * D_ + d0 + threadIdx.x] = tile[threadIdx.x][i];
}

// ------------- GEMM: C[bs] = X[bs] @ W[s] + bias[s]  (Wt = W^T, bf16) -------
// 128x128 tile, BK=32, 256 thr (2x2 waves of 64x64), 16x16x32 bf16 MFMA.
// MODE 0: C bf16 row-major [l][e]; MODE 1: Vt bf16 col-major [e][l];
// MODE 2: C fp32 row-major [l][e] (final output).
template <int MODE>
__global__ __launch_bounds__(256) void gemm_bt(const ushort_t* __restrict__ X,
                                               const ushort_t* __restrict__ Wt,
                                               const float* __restrict__ bias,
                                               void* __restrict__ Cv) {
  __shared__ __attribute__((aligned(16))) ushort_t As[128 * 32];
  __shared__ __attribute__((aligned(16))) ushort_t Bs[128 * 32];

  const int bs = blockIdx.z;
  const int s = bs & 3;
  const int m0 = blockIdx.y * 128;
  const int n0 = blockIdx.x * 128;
  const ushort_t* Xb = X + (size_t)bs * (L_ * D_);
  const ushort_t* Wts = Wt + (size_t)s * (D_ * D_);

  const int t = threadIdx.x;
  const int lane = t & 63;
  const int w = t >> 6;
  const int wm = w >> 1, wn = w & 1;
  const int quad = lane >> 4, cl = lane & 15;

  floatx4 acc[4][4];
  floatx4 zero = {0.f, 0.f, 0.f, 0.f};
#pragma unroll
  for (int i = 0; i < 4; ++i)
#pragma unroll
    for (int j = 0; j < 4; ++j) acc[i][j] = zero;

  const int c0 = t, c1 = t + 256;
  const int ar0 = c0 >> 2, ac0 = (c0 & 3) * 8;
  const int ar1 = c1 >> 2, ac1 = (c1 & 3) * 8;

  for (int k0 = 0; k0 < D_; k0 += 32) {
    gl2lds16(Xb + (size_t)(m0 + ar0) * D_ + k0 + ac0, &As[c0 * 8]);
    gl2lds16(Xb + (size_t)(m0 + ar1) * D_ + k0 + ac1, &As[c1 * 8]);
    gl2lds16(Wts + (size_t)(n0 + ar0) * D_ + k0 + ac0, &Bs[c0 * 8]);
    gl2lds16(Wts + (size_t)(n0 + ar1) * D_ + k0 + ac1, &Bs[c1 * 8]);
    __syncthreads();
    short8 a[4], b[4];
#pragma unroll
    for (int i = 0; i < 4; ++i)
      a[i] = *(const short8*)&As[(wm * 64 + i * 16 + cl) * 32 + quad * 8];
#pragma unroll
    for (int j = 0; j < 4; ++j)
      b[j] = *(const short8*)&Bs[(wn * 64 + j * 16 + cl) * 32 + quad * 8];
#pragma unroll
    for (int i = 0; i < 4; ++i)
#pragma unroll
      for (int j = 0; j < 4; ++j)
        acc[i][j] = __builtin_amdgcn_mfma_f32_16x16x32_bf16(a[i], b[j], acc[i][j], 0, 0, 0);
    __syncthreads();
  }

  // epilogue: C/D layout col=lane&15 (n-dim), row=quad*4+reg (m-dim)
#pragma unroll
  for (int j = 0; j < 4; ++j) {
    const int col = n0 + wn * 64 + j * 16 + cl;
    const float bv = bias[s * D_ + col];
#pragma unroll
    for (int i = 0; i < 4; ++i) {
      const int rb = m0 + wm * 64 + i * 16 + quad * 4;
      if (MODE == 2) {
        float* Cf = (float*)Cv + (size_t)bs * (L_ * D_) + (size_t)rb * D_ + col;
#pragma unroll
        for (int r = 0; r < 4; ++r) Cf[(size_t)r * D_] = acc[i][j][r] + bv;
      } else if (MODE == 0) {
        ushort_t* Cp = (ushort_t*)Cv + (size_t)bs * (L_ * D_) + (size_t)rb * D_ + col;
#pragma unroll
        for (int r = 0; r < 4; ++r) Cp[(size_t)r * D_] = f2bf(acc[i][j][r] + bv);
      } else {
        ushortx4 pk;
#pragma unroll
        for (int r = 0; r < 4; ++r) pk[r] = f2bf(acc[i][j][r] + bv);
        *(ushortx4*)((ushort_t*)Cv + (size_t)bs * (L_ * D_) + (size_t)col * L_ + rb) = pk;
      }
    }
  }
}

// ------------- flash attention: one (bs, h, 64-row Q tile) per block --------
__global__ __launch_bounds__(256) void attn_kernel(const ushort_t* __restrict__ Q,
                                                   const ushort_t* __restrict__ K,
                                                   const ushort_t* __restrict__ Vt,
                                                   ushort_t* __restrict__ O) {
  __shared__ __attribute__((aligned(16))) ushort_t Ks[64 * 64];   // [kv][dk]
  __shared__ __attribute__((aligned(16))) ushort_t Vts[64 * 64];  // [dk][kv]
  __shared__ __attribute__((aligned(16))) ushort_t Ps[4][16 * 72];

  const int qt = blockIdx.x, h = blockIdx.y, bs = blockIdx.z;
  const int q0 = qt * 64;
  const int t = threadIdx.x, lane = t & 63, w = t >> 6;
  const int quad = lane >> 4, cl = lane & 15;
  const size_t act_base = (size_t)bs * (L_ * D_);

  // Q A-fragments for this wave's 16 rows: m=cl, k=quad*8+j (+32)
  const ushort_t* Qp = Q + act_base + (size_t)(q0 + w * 16 + cl) * D_ + h * DK_ + quad * 8;
  const short8 qa0 = *(const short8*)Qp;
  const short8 qa1 = *(const short8*)(Qp + 32);

  floatx4 o[4];
  floatx4 zero = {0.f, 0.f, 0.f, 0.f};
#pragma unroll
  for (int j = 0; j < 4; ++j) o[j] = zero;
  float m_i[4], l_i[4];
#pragma unroll
  for (int r = 0; r < 4; ++r) { m_i[r] = -3.0e38f; l_i[r] = 0.f; }

  const int ntiles = qt + 1;  // causal: kv tiles 0..qt
  for (int it = 0; it < ntiles; ++it) {
    const int kv0 = it * 64;
    {
      const int cA = t, cB = t + 256;
      gl2lds16(K + act_base + (size_t)(kv0 + (cA >> 3)) * D_ + h * DK_ + (cA & 7) * 8, &Ks[cA * 8]);
      gl2lds16(K + act_base + (size_t)(kv0 + (cB >> 3)) * D_ + h * DK_ + (cB & 7) * 8, &Ks[cB * 8]);
      gl2lds16(Vt + act_base + (size_t)(h * DK_ + (cA >> 3)) * L_ + kv0 + (cA & 7) * 8, &Vts[cA * 8]);
      gl2lds16(Vt + act_base + (size_t)(h * DK_ + (cB >> 3)) * L_ + kv0 + (cB & 7) * 8, &Vts[cB * 8]);
    }
    __syncthreads();

    // S = Q K^T * scale
    floatx4 sfr[4];
#pragma unroll
    for (int j = 0; j < 4; ++j) {
      const short8 kb0 = *(const short8*)&Ks[(j * 16 + cl) * 64 + quad * 8];
      const short8 kb1 = *(const short8*)&Ks[(j * 16 + cl) * 64 + 32 + quad * 8];
      floatx4 z = zero;
      z = __builtin_amdgcn_mfma_f32_16x16x32_bf16(qa0, kb0, z, 0, 0, 0);
      z = __builtin_amdgcn_mfma_f32_16x16x32_bf16(qa1, kb1, z, 0, 0, 0);
      sfr[j] = z * 0.125f;
    }

    if (kv0 == q0) {  // diagonal tile: causal mask
#pragma unroll
      for (int j = 0; j < 4; ++j) {
        const int colp = j * 16 + cl;
#pragma unroll
        for (int r = 0; r < 4; ++r)
          if (colp > w * 16 + quad * 4 + r) sfr[j][r] = -1e30f;
      }
    }

    // online softmax; row = w*16 + quad*4 + r lives in the 16 lanes of `quad`
    float mnew[4], alpha[4];
#pragma unroll
    for (int r = 0; r < 4; ++r) {
      float tm = fmaxf(fmaxf(sfr[0][r], sfr[1][r]), fmaxf(sfr[2][r], sfr[3][r]));
      tm = fmaxf(tm, __shfl_xor(tm, 1, 64));
      tm = fmaxf(tm, __shfl_xor(tm, 2, 64));
      tm = fmaxf(tm, __shfl_xor(tm, 4, 64));
      tm = fmaxf(tm, __shfl_xor(tm, 8, 64));
      mnew[r] = fmaxf(m_i[r], tm);
      alpha[r] = __expf(m_i[r] - mnew[r]);
      m_i[r] = mnew[r];
    }
#pragma unroll
    for (int r = 0; r < 4; ++r) {
      float tsv = 0.f;
#pragma unroll
      for (int j = 0; j < 4; ++j) {
        const float p = __expf(sfr[j][r] - mnew[r]);
        sfr[j][r] = p;
        tsv += p;
      }
      tsv += __shfl_xor(tsv, 1, 64);
      tsv += __shfl_xor(tsv, 2, 64);
      tsv += __shfl_xor(tsv, 4, 64);
      tsv += __shfl_xor(tsv, 8, 64);
      l_i[r] = l_i[r] * alpha[r] + tsv;
    }
#pragma unroll
    for (int j = 0; j < 4; ++j)
#pragma unroll
      for (int r = 0; r < 4; ++r) o[j][r] *= alpha[r];

    // P: C-layout -> A-layout via per-wave LDS (row stride 72 ushorts)
#pragma unroll
    for (int j = 0; j < 4; ++j)
#pragma unroll
      for (int r = 0; r < 4; ++r)
        Ps[w][(quad * 4 + r) * 72 + j * 16 + cl] = f2bf(sfr[j][r]);
    __syncthreads();

    // O += P V
#pragma unroll
    for (int kb = 0; kb < 2; ++kb) {
      const short8 pa = *(const short8*)&Ps[w][cl * 72 + kb * 32 + quad * 8];
#pragma unroll
      for (int j = 0; j < 4; ++j) {
        const short8 vb = *(const short8*)&Vts[(j * 16 + cl) * 64 + kb * 32 + quad * 8];
        o[j] = __builtin_amdgcn_mfma_f32_16x16x32_bf16(pa, vb, o[j], 0, 0, 0);
      }
    }
    __syncthreads();
  }

  float inv[4];
#pragma unroll
  for (int r = 0; r < 4; ++r) inv[r] = 1.0f / l_i[r];
#pragma unroll
  for (int j = 0; j < 4; ++j) {
    const int col = h * DK_ + j * 16 + cl;
#pragma unroll
    for (int r = 0; r < 4; ++r) {
      const int row = q0 + w * 16 + quad * 4 + r;
      O[act_base + (size_t)row * D_ + col] = f2bf(o[j][r] * inv[r]);
    }
  }
}

extern "C" void kernel_launch(void* const* d_in, const int* in_sizes, int n_in,
                              void* d_out, int out_size, void* d_ws, size_t ws_size,
                              hipStream_t stream) {
  const float* x  = (const float*)d_in[0];
  const float* Wq = (const float*)d_in[1];
  const float* Wk = (const float*)d_in[2];
  const float* Wv = (const float*)d_in[3];
  const float* Wo = (const float*)d_in[4];
  const float* bq = (const float*)d_in[5];
  const float* bk = (const float*)d_in[6];
  const float* bv = (const float*)d_in[7];
  const float* bo = (const float*)d_in[8];

  const size_t WT_SZ = (size_t)SPLIT_ * D_ * D_;  // 4 Mi elements
  const size_t ACT_SZ = (size_t)B_ * SEQ_ * D_;   // 16 Mi elements

  // ws layout (bf16): xbf[16Mi] | wtq..wto[4x4Mi] | Vt[16Mi]  => 96 MiB total
  ushort_t* ws0 = (ushort_t*)d_ws;
  ushort_t* xbf = ws0;
  ushort_t* wtq = xbf + ACT_SZ;
  ushort_t* wtk = wtq + WT_SZ;
  ushort_t* wtv = wtk + WT_SZ;
  ushort_t* wto = wtv + WT_SZ;
  ushort_t* Vtb = wto + WT_SZ;
  // d_out (16Mi fp32 = 64 MiB) doubles as Q/K bf16 scratch until the final GEMM
  ushort_t* Qb = (ushort_t*)d_out;
  ushort_t* Kb = Qb + ACT_SZ;
  // attention output reuses xbf (x is dead after the V projection)
  ushort_t* Ob = xbf;

  convert_x<<<ACT_SZ / 1024, 256, 0, stream>>>(x, xbf);

  dim3 tb(32, 8, 1), tg(32, 32, 4);
  wt_convert<<<tg, tb, 0, stream>>>(Wq, wtq);
  wt_convert<<<tg, tb, 0, stream>>>(Wk, wtk);
  wt_convert<<<tg, tb, 0, stream>>>(Wv, wtv);
  wt_convert<<<tg, tb, 0, stream>>>(Wo, wto);

  dim3 gb(256, 1, 1), gg(8, 8, 16);
  gemm_bt<0><<<gg, gb, 0, stream>>>(xbf, wtq, bq, Qb);
  gemm_bt<0><<<gg, gb, 0, stream>>>(xbf, wtk, bk, Kb);
  gemm_bt<1><<<gg, gb, 0, stream>>>(xbf, wtv, bv, Vtb);

  dim3 ag(16, 16, 16);
  attn_kernel<<<ag, dim3(256, 1, 1), 0, stream>>>(Qb, Kb, Vtb, Ob);

  gemm_bt<2><<<gg, gb, 0, stream>>>(Ob, wto, bo, d_out);
}

// Round 3
// 533.948 us; speedup vs baseline: 1.2766x; 1.2766x over previous
//
#include <hip/hip_runtime.h>
#include <stdint.h>

#define H_ 16
#define D_ 1024
#define SPLIT_ 4
#define DK_ 64
#define B_ 4
#define SEQ_ 4096
#define L_ 1024

typedef unsigned short ushort_t;
typedef __attribute__((ext_vector_type(8))) short short8;
typedef __attribute__((ext_vector_type(4))) float floatx4;
typedef __attribute__((ext_vector_type(4))) unsigned short ushortx4;

__device__ __forceinline__ ushort_t f2bf(float f) {
  union { float f; unsigned u; } cv; cv.f = f;
  unsigned u = cv.u;
  return (ushort_t)((u + 0x7fffu + ((u >> 16) & 1u)) >> 16);
}

// async 16B global->LDS (dest must be wave-uniform base + lane*16)
__device__ __forceinline__ void gl2lds16(const ushort_t* g, ushort_t* l) {
  __builtin_amdgcn_global_load_lds(
      (const __attribute__((address_space(1))) uint32_t*)g,
      (__attribute__((address_space(3))) uint32_t*)l, 16, 0, 0);
}

// ------------- x: fp32 -> bf16 (contiguous) ---------------------------------
__global__ __launch_bounds__(256) void convert_x(const float* __restrict__ X,
                                                 ushort_t* __restrict__ Y) {
  const int i = blockIdx.x * 256 + threadIdx.x;
  const float4 v = ((const float4*)X)[i];
  ushortx4 o;
  o[0] = f2bf(v.x); o[1] = f2bf(v.y); o[2] = f2bf(v.z); o[3] = f2bf(v.w);
  ((ushortx4*)Y)[i] = o;
}

// ------------- W[s][d][e] fp32 -> Wt[s][e][d] bf16 --------------------------
__global__ __launch_bounds__(256) void wt_convert(const float* __restrict__ W,
                                                  ushort_t* __restrict__ Wt) {
  __shared__ ushort_t tile[32][33];
  const int s = blockIdx.z;
  const float* Ws = W + (size_t)s * D_ * D_;
  ushort_t* Wts = Wt + (size_t)s * D_ * D_;
  const int e0 = blockIdx.x * 32, d0 = blockIdx.y * 32;
  for (int i = threadIdx.y; i < 32; i += 8)
    tile[i][threadIdx.x] = f2bf(Ws[(size_t)(d0 + i) * D_ + e0 + threadIdx.x]);
  __syncthreads();
  for (int i = threadIdx.y; i < 32; i += 8)
    Wts[(size_t)(e0 + i) * D_ + d0 + threadIdx.x] = tile[threadIdx.x][i];
}

// ------------- GEMM: C[bs] = X[bs] @ W[s] + bias[s]  (Wt = W^T, bf16) -------
// 128x128 tile, BK=32, 256 thr (2x2 waves of 64x64), 16x16x32 bf16 MFMA.
// LDS layout XOR-swizzled: (row, colchunk C in 0..3) stored at chunk
// row*4 + (C ^ (row&3)) -> B-frag ds_read_b128 is <=2-way bank conflicted.
// MODE 0: C bf16 row-major [l][e]; MODE 1: Vt bf16 col-major [e][l];
// MODE 2: C fp32 row-major [l][e] (final output).
template <int MODE>
__global__ __launch_bounds__(256) void gemm_bt(const ushort_t* __restrict__ X,
                                               const ushort_t* __restrict__ Wt,
                                               const float* __restrict__ bias,
                                               void* __restrict__ Cv) {
  __shared__ __attribute__((aligned(16))) ushort_t As[128 * 32];
  __shared__ __attribute__((aligned(16))) ushort_t Bs[128 * 32];

  const int bs = blockIdx.z;
  const int s = bs & 3;
  const int m0 = blockIdx.y * 128;
  const int n0 = blockIdx.x * 128;
  const ushort_t* Xb = X + (size_t)bs * (L_ * D_);
  const ushort_t* Wts = Wt + (size_t)s * (D_ * D_);

  const int t = threadIdx.x;
  const int lane = t & 63;
  const int w = t >> 6;
  const int wm = w >> 1, wn = w & 1;
  const int quad = lane >> 4, cl = lane & 15;

  floatx4 acc[4][4];
  floatx4 zero = {0.f, 0.f, 0.f, 0.f};
#pragma unroll
  for (int i = 0; i < 4; ++i)
#pragma unroll
    for (int j = 0; j < 4; ++j) acc[i][j] = zero;

  // staging: thread t fills LDS chunks c0=t, c1=t+256 (chunk = 16B = 8 ushorts)
  const int c0 = t, c1 = t + 256;
  const int r0 = c0 >> 2, cc0 = ((c0 & 3) ^ (r0 & 3)) * 8;
  const int r1 = c1 >> 2, cc1 = ((c1 & 3) ^ (r1 & 3)) * 8;
  const int sw = (quad ^ (cl & 3)) * 8;  // swizzled in-row offset for frag reads

  for (int k0 = 0; k0 < D_; k0 += 32) {
    gl2lds16(Xb + (size_t)(m0 + r0) * D_ + k0 + cc0, &As[c0 * 8]);
    gl2lds16(Xb + (size_t)(m0 + r1) * D_ + k0 + cc1, &As[c1 * 8]);
    gl2lds16(Wts + (size_t)(n0 + r0) * D_ + k0 + cc0, &Bs[c0 * 8]);
    gl2lds16(Wts + (size_t)(n0 + r1) * D_ + k0 + cc1, &Bs[c1 * 8]);
    __syncthreads();
    short8 a[4], b[4];
#pragma unroll
    for (int i = 0; i < 4; ++i)
      a[i] = *(const short8*)&As[(wm * 64 + i * 16 + cl) * 32 + sw];
#pragma unroll
    for (int j = 0; j < 4; ++j)
      b[j] = *(const short8*)&Bs[(wn * 64 + j * 16 + cl) * 32 + sw];
#pragma unroll
    for (int i = 0; i < 4; ++i)
#pragma unroll
      for (int j = 0; j < 4; ++j)
        acc[i][j] = __builtin_amdgcn_mfma_f32_16x16x32_bf16(a[i], b[j], acc[i][j], 0, 0, 0);
    __syncthreads();
  }

  // epilogue: C/D layout col=lane&15 (n-dim), row=quad*4+reg (m-dim)
#pragma unroll
  for (int j = 0; j < 4; ++j) {
    const int col = n0 + wn * 64 + j * 16 + cl;
    const float bv = bias[s * D_ + col];
#pragma unroll
    for (int i = 0; i < 4; ++i) {
      const int rb = m0 + wm * 64 + i * 16 + quad * 4;
      if (MODE == 2) {
        float* Cf = (float*)Cv + (size_t)bs * (L_ * D_) + (size_t)rb * D_ + col;
#pragma unroll
        for (int r = 0; r < 4; ++r) Cf[(size_t)r * D_] = acc[i][j][r] + bv;
      } else if (MODE == 0) {
        ushort_t* Cp = (ushort_t*)Cv + (size_t)bs * (L_ * D_) + (size_t)rb * D_ + col;
#pragma unroll
        for (int r = 0; r < 4; ++r) Cp[(size_t)r * D_] = f2bf(acc[i][j][r] + bv);
      } else {
        ushortx4 pk;
#pragma unroll
        for (int r = 0; r < 4; ++r) pk[r] = f2bf(acc[i][j][r] + bv);
        *(ushortx4*)((ushort_t*)Cv + (size_t)bs * (L_ * D_) + (size_t)col * L_ + rb) = pk;
      }
    }
  }
}

// ------------- flash attention ----------------------------------------------
// Block p handles q-tiles {p, 15-p} (uniform 17 kv-tiles). Double-buffered
// K/V with ONE barrier per tile; P transpose per-wave (no barrier); row-sum
// via ones-operand MFMA (l rides along like an extra O column).
__global__ __launch_bounds__(256) void attn_kernel(const ushort_t* __restrict__ Q,
                                                   const ushort_t* __restrict__ K,
                                                   const ushort_t* __restrict__ Vt,
                                                   ushort_t* __restrict__ O) {
  __shared__ __attribute__((aligned(16))) ushort_t Ks[2][64 * 64];   // [kv][dk] swz
  __shared__ __attribute__((aligned(16))) ushort_t Vts[2][64 * 64];  // [dk][kv] swz
  __shared__ __attribute__((aligned(16))) ushort_t Ps[4][1280];      // quad-skewed

  const int p = blockIdx.x, h = blockIdx.y, bs = blockIdx.z;
  const int t = threadIdx.x, lane = t & 63, w = t >> 6;
  const int quad = lane >> 4, cl = lane & 15;
  const size_t act_base = (size_t)bs * (L_ * D_);
  const int qtA = p, qtB = 15 - p;
  const int seg1 = p + 1;  // iteration index where the 2nd q-tile starts
  const int NIT = 17;

  // staging chunk geometry (chunk = 16B): LDS chunk c <- row c>>3, col ((c&7)^(row&7))*8
  const int cA = t, cB = t + 256;
  const int rA = cA >> 3, ccA = ((cA & 7) ^ (rA & 7)) * 8;
  const int rB = cB >> 3, ccB = ((cB & 7) ^ (rB & 7)) * 8;

  const short8 ones = {0x3F80, 0x3F80, 0x3F80, 0x3F80, 0x3F80, 0x3F80, 0x3F80, 0x3F80};
  floatx4 zero = {0.f, 0.f, 0.f, 0.f};

  short8 qa0, qa1;
  floatx4 o[4], lsum;
  float m_i[4];
  int qt = qtA;

  auto prefetch = [&](int i) {
    const int kvt = (i < seg1) ? i : (i - seg1);
    const int buf = i & 1;
    const ushort_t* Kg = K + act_base + (size_t)(kvt * 64) * D_ + h * DK_;
    const ushort_t* Vg = Vt + act_base + (size_t)(h * DK_) * L_ + kvt * 64;
    gl2lds16(Kg + (size_t)rA * D_ + ccA, &Ks[buf][cA * 8]);
    gl2lds16(Kg + (size_t)rB * D_ + ccB, &Ks[buf][cB * 8]);
    gl2lds16(Vg + (size_t)rA * L_ + ccA, &Vts[buf][cA * 8]);
    gl2lds16(Vg + (size_t)rB * L_ + ccB, &Vts[buf][cB * 8]);
  };

  prefetch(0);
  for (int i = 0; i < NIT; ++i) {
    __syncthreads();               // drains buf[i&1] loads; prior reads of buf[(i+1)&1] done
    if (i + 1 < NIT) prefetch(i + 1);
    const int buf = i & 1;

    if (i == 0 || i == seg1) {     // segment start: new q-tile
      qt = (i == 0) ? qtA : qtB;
      const ushort_t* Qp = Q + act_base + (size_t)(qt * 64 + w * 16 + cl) * D_ + h * DK_ + quad * 8;
      qa0 = *(const short8*)Qp;
      qa1 = *(const short8*)(Qp + 32);
#pragma unroll
      for (int j = 0; j < 4; ++j) o[j] = zero;
      lsum = zero;
#pragma unroll
      for (int r = 0; r < 4; ++r) m_i[r] = -3.0e38f;
    }
    const int kvt = (i < seg1) ? i : (i - seg1);

    // S = Q K^T * scale  (swizzled B-frag reads: chunk C = kb*4+quad, xor cl&7)
    floatx4 sfr[4];
#pragma unroll
    for (int j = 0; j < 4; ++j) {
      const int row = (j * 16 + cl) * 64;
      const short8 kb0 = *(const short8*)&Ks[buf][row + ((quad ^ (cl & 7)) * 8)];
      const short8 kb1 = *(const short8*)&Ks[buf][row + (((4 + quad) ^ (cl & 7)) * 8)];
      floatx4 z = zero;
      z = __builtin_amdgcn_mfma_f32_16x16x32_bf16(qa0, kb0, z, 0, 0, 0);
      z = __builtin_amdgcn_mfma_f32_16x16x32_bf16(qa1, kb1, z, 0, 0, 0);
      sfr[j] = z * 0.125f;
    }

    if (kvt == qt) {  // diagonal tile: causal mask
#pragma unroll
      for (int j = 0; j < 4; ++j) {
        const int colp = j * 16 + cl;
#pragma unroll
        for (int r = 0; r < 4; ++r)
          if (colp > w * 16 + quad * 4 + r) sfr[j][r] = -1e30f;
      }
    }

    // online softmax max-update; row r data lives in the 16 lanes of `quad`
    float alpha[4];
#pragma unroll
    for (int r = 0; r < 4; ++r) {
      float tm = fmaxf(fmaxf(sfr[0][r], sfr[1][r]), fmaxf(sfr[2][r], sfr[3][r]));
      tm = fmaxf(tm, __shfl_xor(tm, 1, 64));
      tm = fmaxf(tm, __shfl_xor(tm, 2, 64));
      tm = fmaxf(tm, __shfl_xor(tm, 4, 64));
      tm = fmaxf(tm, __shfl_xor(tm, 8, 64));
      const float mnew = fmaxf(m_i[r], tm);
      alpha[r] = __expf(m_i[r] - mnew);
      m_i[r] = mnew;
    }
#pragma unroll
    for (int j = 0; j < 4; ++j)
#pragma unroll
      for (int r = 0; r < 4; ++r)
        sfr[j][r] = __expf(sfr[j][r] - m_i[r]);

    // P: C-layout -> A-layout via per-wave LDS (stride 72, quad*16 skew)
#pragma unroll
    for (int j = 0; j < 4; ++j)
#pragma unroll
      for (int r = 0; r < 4; ++r)
        Ps[w][(quad * 4 + r) * 72 + quad * 16 + j * 16 + cl] = f2bf(sfr[j][r]);

    // rescale O and l by alpha
#pragma unroll
    for (int j = 0; j < 4; ++j)
#pragma unroll
      for (int r = 0; r < 4; ++r) o[j][r] *= alpha[r];
#pragma unroll
    for (int r = 0; r < 4; ++r) lsum[r] *= alpha[r];

    // O += P V ; l += P @ ones   (pa row cl with skew (cl>>2)*16)
#pragma unroll
    for (int kb = 0; kb < 2; ++kb) {
      const short8 pa = *(const short8*)&Ps[w][cl * 72 + (cl >> 2) * 16 + kb * 32 + quad * 8];
#pragma unroll
      for (int j = 0; j < 4; ++j) {
        const int row = (j * 16 + cl) * 64;
        const short8 vb = *(const short8*)&Vts[buf][row + (((kb * 4 + quad) ^ (cl & 7)) * 8)];
        o[j] = __builtin_amdgcn_mfma_f32_16x16x32_bf16(pa, vb, o[j], 0, 0, 0);
      }
      lsum = __builtin_amdgcn_mfma_f32_16x16x32_bf16(pa, ones, lsum, 0, 0, 0);
    }

    if (i == seg1 - 1 || i == NIT - 1) {  // segment end: normalize + store
      float inv[4];
#pragma unroll
      for (int r = 0; r < 4; ++r) inv[r] = 1.0f / lsum[r];
#pragma unroll
      for (int j = 0; j < 4; ++j) {
        const int col = h * DK_ + j * 16 + cl;
#pragma unroll
        for (int r = 0; r < 4; ++r) {
          const int row = qt * 64 + w * 16 + quad * 4 + r;
          O[act_base + (size_t)row * D_ + col] = f2bf(o[j][r] * inv[r]);
        }
      }
    }
  }
}

extern "C" void kernel_launch(void* const* d_in, const int* in_sizes, int n_in,
                              void* d_out, int out_size, void* d_ws, size_t ws_size,
                              hipStream_t stream) {
  const float* x  = (const float*)d_in[0];
  const float* Wq = (const float*)d_in[1];
  const float* Wk = (const float*)d_in[2];
  const float* Wv = (const float*)d_in[3];
  const float* Wo = (const float*)d_in[4];
  const float* bq = (const float*)d_in[5];
  const float* bk = (const float*)d_in[6];
  const float* bv = (const float*)d_in[7];
  const float* bo = (const float*)d_in[8];

  const size_t WT_SZ = (size_t)SPLIT_ * D_ * D_;  // 4 Mi elements
  const size_t ACT_SZ = (size_t)B_ * SEQ_ * D_;   // 16 Mi elements

  // ws layout (bf16): xbf[16Mi] | wtq..wto[4x4Mi] | Vt[16Mi]  => 96 MiB total
  ushort_t* ws0 = (ushort_t*)d_ws;
  ushort_t* xbf = ws0;
  ushort_t* wtq = xbf + ACT_SZ;
  ushort_t* wtk = wtq + WT_SZ;
  ushort_t* wtv = wtk + WT_SZ;
  ushort_t* wto = wtv + WT_SZ;
  ushort_t* Vtb = wto + WT_SZ;
  // d_out (16Mi fp32 = 64 MiB) doubles as Q/K bf16 scratch until the final GEMM
  ushort_t* Qb = (ushort_t*)d_out;
  ushort_t* Kb = Qb + ACT_SZ;
  // attention output reuses xbf (x is dead after the V projection)
  ushort_t* Ob = xbf;

  convert_x<<<ACT_SZ / 1024, 256, 0, stream>>>(x, xbf);

  dim3 tb(32, 8, 1), tg(32, 32, 4);
  wt_convert<<<tg, tb, 0, stream>>>(Wq, wtq);
  wt_convert<<<tg, tb, 0, stream>>>(Wk, wtk);
  wt_convert<<<tg, tb, 0, stream>>>(Wv, wtv);
  wt_convert<<<tg, tb, 0, stream>>>(Wo, wto);

  dim3 gb(256, 1, 1), gg(8, 8, 16);
  gemm_bt<0><<<gg, gb, 0, stream>>>(xbf, wtq, bq, Qb);
  gemm_bt<0><<<gg, gb, 0, stream>>>(xbf, wtk, bk, Kb);
  gemm_bt<1><<<gg, gb, 0, stream>>>(xbf, wtv, bv, Vtb);

  dim3 ag(8, 16, 16);
  attn_kernel<<<ag, dim3(256, 1, 1), 0, stream>>>(Qb, Kb, Vtb, Ob);

  gemm_bt<2><<<gg, gb, 0, stream>>>(Ob, wto, bo, d_out);
}

// Round 4
// 507.243 us; speedup vs baseline: 1.3438x; 1.0526x over previous
//
#include <hip/hip_runtime.h>
#include <stdint.h>

#define H_ 16
#define D_ 1024
#define SPLIT_ 4
#define DK_ 64
#define B_ 4
#define SEQ_ 4096
#define L_ 1024

// 0.125 * log2(e): folded into Wq/bq so attn softmax runs in exp2 domain.
#define QSC 0.18033688f

typedef unsigned short ushort_t;
typedef __attribute__((ext_vector_type(8))) short short8;
typedef __attribute__((ext_vector_type(4))) float floatx4;
typedef __attribute__((ext_vector_type(4))) unsigned short ushortx4;

__device__ __forceinline__ ushort_t f2bf(float f) {   // RNE
  union { float f; unsigned u; } cv; cv.f = f;
  unsigned u = cv.u;
  return (ushort_t)((u + 0x7fffu + ((u >> 16) & 1u)) >> 16);
}

// pack two floats -> bf16x2 (truncating) in one v_perm_b32
__device__ __forceinline__ uint32_t pack_bf_trunc(float x, float y) {
#if __has_builtin(__builtin_amdgcn_perm)
  return __builtin_amdgcn_perm(__float_as_uint(y), __float_as_uint(x), 0x07060302u);
#else
  return (__float_as_uint(y) & 0xffff0000u) | (__float_as_uint(x) >> 16);
#endif
}

__device__ __forceinline__ float exp2f_fast(float x) {
#if __has_builtin(__builtin_amdgcn_exp2f)
  return __builtin_amdgcn_exp2f(x);
#else
  return exp2f(x);
#endif
}

// async 16B global->LDS (dest must be wave-uniform base + lane*16)
__device__ __forceinline__ void gl2lds16(const ushort_t* g, ushort_t* l) {
  __builtin_amdgcn_global_load_lds(
      (const __attribute__((address_space(1))) uint32_t*)g,
      (__attribute__((address_space(3))) uint32_t*)l, 16, 0, 0);
}

// ------------- x: fp32 -> bf16 (contiguous) ---------------------------------
__global__ __launch_bounds__(256) void convert_x(const float* __restrict__ X,
                                                 ushort_t* __restrict__ Y) {
  const int i = blockIdx.x * 256 + threadIdx.x;
  const float4 v = ((const float4*)X)[i];
  ushortx4 o;
  o[0] = f2bf(v.x); o[1] = f2bf(v.y); o[2] = f2bf(v.z); o[3] = f2bf(v.w);
  ((ushortx4*)Y)[i] = o;
}

// ------------- all 4 weights: W[s][d][e] fp32 -> Wt[mat][s][e][d] bf16 ------
__global__ __launch_bounds__(256) void wt_convert_all(const float* __restrict__ W0,
                                                      const float* __restrict__ W1,
                                                      const float* __restrict__ W2,
                                                      const float* __restrict__ W3,
                                                      ushort_t* __restrict__ Wt) {
  __shared__ ushort_t tile[32][33];
  const int z = blockIdx.z, mat = z >> 2, s = z & 3;
  const float* W = (mat == 0) ? W0 : (mat == 1) ? W1 : (mat == 2) ? W2 : W3;
  const float scale = (mat == 0) ? QSC : 1.0f;
  const float* Ws = W + (size_t)s * D_ * D_;
  ushort_t* Wts = Wt + ((size_t)mat * SPLIT_ + s) * D_ * D_;
  const int e0 = blockIdx.x * 32, d0 = blockIdx.y * 32;
  for (int i = threadIdx.y; i < 32; i += 8)
    tile[i][threadIdx.x] = f2bf(Ws[(size_t)(d0 + i) * D_ + e0 + threadIdx.x] * scale);
  __syncthreads();
  for (int i = threadIdx.y; i < 32; i += 8)
    Wts[(size_t)(e0 + i) * D_ + d0 + threadIdx.x] = tile[threadIdx.x][i];
}

// ------------- GEMM: C[bs] = X[bs] @ W[s] + bias[s]*bscale  (Wt = W^T) ------
// 128x128 tile, BK=32, 256 thr (2x2 waves of 64x64), 16x16x32 bf16 MFMA.
// MODE 0: C bf16 row-major [l][e] (LDS-staged coalesced epilogue)
// MODE 1: Vt bf16 col-major [e][l] (LDS-staged coalesced epilogue)
// MODE 2: C fp32 row-major [l][e] (direct stores, final output)
template <int MODE>
__global__ __launch_bounds__(256) void gemm_bt(const ushort_t* __restrict__ X,
                                               const ushort_t* __restrict__ Wt,
                                               const float* __restrict__ bias,
                                               float bscale,
                                               void* __restrict__ Cv) {
  __shared__ __attribute__((aligned(16))) ushort_t SH[8192];  // As|Bs, then CT
  ushort_t* As = SH;
  ushort_t* Bs = SH + 4096;

  const int bs = blockIdx.z;
  const int s = bs & 3;
  const int m0 = blockIdx.y * 128;
  const int n0 = blockIdx.x * 128;
  const ushort_t* Xb = X + (size_t)bs * (L_ * D_);
  const ushort_t* Wts = Wt + (size_t)s * (D_ * D_);

  const int t = threadIdx.x;
  const int lane = t & 63;
  const int w = t >> 6;
  const int wm = w >> 1, wn = w & 1;
  const int quad = lane >> 4, cl = lane & 15;

  floatx4 acc[4][4];
  floatx4 zero = {0.f, 0.f, 0.f, 0.f};
#pragma unroll
  for (int i = 0; i < 4; ++i)
#pragma unroll
    for (int j = 0; j < 4; ++j) acc[i][j] = zero;

  const int c0 = t, c1 = t + 256;
  const int r0 = c0 >> 2, cc0 = ((c0 & 3) ^ (r0 & 3)) * 8;
  const int r1 = c1 >> 2, cc1 = ((c1 & 3) ^ (r1 & 3)) * 8;
  const int sw = (quad ^ (cl & 3)) * 8;

  for (int k0 = 0; k0 < D_; k0 += 32) {
    gl2lds16(Xb + (size_t)(m0 + r0) * D_ + k0 + cc0, &As[c0 * 8]);
    gl2lds16(Xb + (size_t)(m0 + r1) * D_ + k0 + cc1, &As[c1 * 8]);
    gl2lds16(Wts + (size_t)(n0 + r0) * D_ + k0 + cc0, &Bs[c0 * 8]);
    gl2lds16(Wts + (size_t)(n0 + r1) * D_ + k0 + cc1, &Bs[c1 * 8]);
    __syncthreads();
    short8 a[4], b[4];
#pragma unroll
    for (int i = 0; i < 4; ++i)
      a[i] = *(const short8*)&As[(wm * 64 + i * 16 + cl) * 32 + sw];
#pragma unroll
    for (int j = 0; j < 4; ++j)
      b[j] = *(const short8*)&Bs[(wn * 64 + j * 16 + cl) * 32 + sw];
#pragma unroll
    for (int i = 0; i < 4; ++i)
#pragma unroll
      for (int j = 0; j < 4; ++j)
        acc[i][j] = __builtin_amdgcn_mfma_f32_16x16x32_bf16(a[i], b[j], acc[i][j], 0, 0, 0);
    __syncthreads();
  }

  // bias per output column (C/D layout: col=lane&15, row=quad*4+reg)
  float bvj[4];
#pragma unroll
  for (int j = 0; j < 4; ++j)
    bvj[j] = bias[s * D_ + n0 + wn * 64 + j * 16 + cl] * bscale;

  if (MODE == 2) {  // direct fp32 stores (64B segments per quad-row)
#pragma unroll
    for (int j = 0; j < 4; ++j) {
      const int col = n0 + wn * 64 + j * 16 + cl;
#pragma unroll
      for (int i = 0; i < 4; ++i) {
        const int rb = m0 + wm * 64 + i * 16 + quad * 4;
        float* Cf = (float*)Cv + (size_t)bs * (L_ * D_) + (size_t)rb * D_ + col;
#pragma unroll
        for (int r = 0; r < 4; ++r) Cf[(size_t)r * D_] = acc[i][j][r] + bvj[j];
      }
    }
    return;
  }

  // LDS-staged coalesced epilogue. CT = 64x128 bf16 tile (16KB), XOR-swizzled
  ushort_t* CT = SH;
#pragma unroll
  for (int ph = 0; ph < 2; ++ph) {
    __syncthreads();
    if (MODE == 0 ? (wm == ph) : (wn == ph)) {
#pragma unroll
      for (int i = 0; i < 4; ++i)
#pragma unroll
        for (int j = 0; j < 4; ++j)
#pragma unroll
          for (int r = 0; r < 4; ++r) {
            int row, col;
            if (MODE == 0) { row = i * 16 + quad * 4 + r; col = wn * 64 + j * 16 + cl; }
            else           { row = j * 16 + cl;           col = wm * 64 + i * 16 + quad * 4 + r; }
            const int ch = col >> 3, off = col & 7;
            CT[row * 128 + ((ch ^ (row & 15)) << 3) + off] = f2bf(acc[i][j][r] + bvj[j]);
          }
    }
    __syncthreads();
#pragma unroll
    for (int pass = 0; pass < 4; ++pass) {
      const int row = pass * 16 + (t >> 4);
      const int ck = t & 15;
      const short8 v = *(const short8*)&CT[row * 128 + ((ck ^ (row & 15)) << 3)];
      if (MODE == 0) {
        *(short8*)((ushort_t*)Cv + (size_t)bs * (L_ * D_) +
                   (size_t)(m0 + ph * 64 + row) * D_ + n0 + ck * 8) = v;
      } else {
        *(short8*)((ushort_t*)Cv + (size_t)bs * (L_ * D_) +
                   (size_t)(n0 + ph * 64 + row) * L_ + m0 + ck * 8) = v;
      }
    }
  }
}

// ------------- flash attention (transposed-S form) --------------------------
// Block p: q-tiles {p, 15-p} (uniform 17 kv-tiles). One barrier/tile,
// double-buffered K/V. S^T = K Q^T so each lane owns one q-row: softmax is
// in-lane + 2 shfls; P^T packed pairs -> b32 LDS writes; O^T = V^T P^T.
__global__ __launch_bounds__(256) void attn_kernel(const ushort_t* __restrict__ Q,
                                                   const ushort_t* __restrict__ K,
                                                   const ushort_t* __restrict__ Vt,
                                                   ushort_t* __restrict__ O) {
  __shared__ __attribute__((aligned(16))) ushort_t Ks[2][64 * 64];   // [kv][dk] swz
  __shared__ __attribute__((aligned(16))) ushort_t Vts[2][64 * 64];  // [dk][kv] swz
  __shared__ __attribute__((aligned(16))) ushort_t PT[4][1152];      // [q=cl][kv], stride 72

  const int p = blockIdx.x, h = blockIdx.y, bs = blockIdx.z;
  const int t = threadIdx.x, lane = t & 63, w = t >> 6;
  const int quad = lane >> 4, cl = lane & 15;
  const size_t act_base = (size_t)bs * (L_ * D_);
  const int qtA = p, qtB = 15 - p;
  const int seg1 = p + 1;
  const int NIT = 17;

  const int cA = t, cB = t + 256;
  const int rA = cA >> 3, ccA = ((cA & 7) ^ (rA & 7)) * 8;
  const int rB = cB >> 3, ccB = ((cB & 7) ^ (rB & 7)) * 8;

  // incremental prefetch pointers (kvt=0 bases)
  const ushort_t* kbaseA = K + act_base + (size_t)rA * D_ + h * DK_ + ccA;
  const ushort_t* kbaseB = K + act_base + (size_t)rB * D_ + h * DK_ + ccB;
  const ushort_t* vbaseA = Vt + act_base + (size_t)(h * DK_ + rA) * L_ + ccA;
  const ushort_t* vbaseB = Vt + act_base + (size_t)(h * DK_ + rB) * L_ + ccB;
  const ushort_t *pKA = kbaseA, *pKB = kbaseB, *pVA = vbaseA, *pVB = vbaseB;
  const size_t kstep = (size_t)64 * D_, vstep = 64;

  floatx4 zero = {0.f, 0.f, 0.f, 0.f};
  short8 qa0, qa1;          // Q fragment (B-operand): lane=q-row, k contiguous
  floatx4 o[4];             // O^T tiles over dk: lane col=q, rows=dk
  float m_i, l_i;
  int qt = qtA;

  // issue kvt=0 into buf 0
  gl2lds16(pKA, &Ks[0][cA * 8]);
  gl2lds16(pKB, &Ks[0][cB * 8]);
  gl2lds16(pVA, &Vts[0][cA * 8]);
  gl2lds16(pVB, &Vts[0][cB * 8]);

  for (int i = 0; i < NIT; ++i) {
    __syncthreads();
    if (i + 1 < NIT) {
      const int nk = (i + 1 < seg1) ? i + 1 : i + 1 - seg1;
      if (nk == 0) { pKA = kbaseA; pKB = kbaseB; pVA = vbaseA; pVB = vbaseB; }
      else { pKA += kstep; pKB += kstep; pVA += vstep; pVB += vstep; }
      const int nb = (i + 1) & 1;
      gl2lds16(pKA, &Ks[nb][cA * 8]);
      gl2lds16(pKB, &Ks[nb][cB * 8]);
      gl2lds16(pVA, &Vts[nb][cA * 8]);
      gl2lds16(pVB, &Vts[nb][cB * 8]);
    }
    const int buf = i & 1;

    if (i == 0 || i == seg1) {  // new q-tile
      qt = (i == 0) ? qtA : qtB;
      const ushort_t* Qp = Q + act_base + (size_t)(qt * 64 + w * 16 + cl) * D_ + h * DK_ + quad * 8;
      qa0 = *(const short8*)Qp;
      qa1 = *(const short8*)(Qp + 32);
#pragma unroll
      for (int j = 0; j < 4; ++j) o[j] = zero;
      m_i = -3.0e38f; l_i = 0.f;
    }
    const bool segend = (i == seg1 - 1) || (i == NIT - 1);  // also == diagonal tile

    // S^T = K Q^T (already in exp2 domain: Wq pre-scaled by 0.125*log2e)
    floatx4 st[4];
#pragma unroll
    for (int j = 0; j < 4; ++j) {
      const int row = (j * 16 + cl) * 64;
      const short8 ka0 = *(const short8*)&Ks[buf][row + ((quad ^ (cl & 7)) * 8)];
      const short8 ka1 = *(const short8*)&Ks[buf][row + (((4 + quad) ^ (cl & 7)) * 8)];
      floatx4 z = zero;
      z = __builtin_amdgcn_mfma_f32_16x16x32_bf16(ka0, qa0, z, 0, 0, 0);
      z = __builtin_amdgcn_mfma_f32_16x16x32_bf16(ka1, qa1, z, 0, 0, 0);
      st[j] = z;
    }

    if (segend) {  // diagonal tile: causal mask (kv_local > q_local)
      const int ql = w * 16 + cl;
#pragma unroll
      for (int j = 0; j < 4; ++j)
#pragma unroll
        for (int r = 0; r < 4; ++r)
          if (j * 16 + quad * 4 + r > ql) st[j][r] = -1e30f;
    }

    // per-lane softmax over this lane's 16 kv values + 2 shfls across quads
    float tm = fmaxf(fmaxf(fmaxf(st[0][0], st[0][1]), fmaxf(st[0][2], st[0][3])),
                     fmaxf(fmaxf(st[1][0], st[1][1]), fmaxf(st[1][2], st[1][3])));
    tm = fmaxf(tm, fmaxf(fmaxf(fmaxf(st[2][0], st[2][1]), fmaxf(st[2][2], st[2][3])),
                         fmaxf(fmaxf(st[3][0], st[3][1]), fmaxf(st[3][2], st[3][3]))));
    tm = fmaxf(tm, __shfl_xor(tm, 16, 64));
    tm = fmaxf(tm, __shfl_xor(tm, 32, 64));
    const float mnew = fmaxf(m_i, tm);
    const float alpha = exp2f_fast(m_i - mnew);
    m_i = mnew;

    float tsv = 0.f;
#pragma unroll
    for (int j = 0; j < 4; ++j)
#pragma unroll
      for (int r = 0; r < 4; ++r) {
        st[j][r] = exp2f_fast(st[j][r] - mnew);
        tsv += st[j][r];
      }
    tsv += __shfl_xor(tsv, 16, 64);
    tsv += __shfl_xor(tsv, 32, 64);
    l_i = l_i * alpha + tsv;

    // P^T pairs -> LDS (b32 writes, kv-consecutive within a lane)
#pragma unroll
    for (int j = 0; j < 4; ++j) {
      const int base = cl * 72 + j * 16 + quad * 4;
      *(uint32_t*)&PT[w][base] = pack_bf_trunc(st[j][0], st[j][1]);
      *(uint32_t*)&PT[w][base + 2] = pack_bf_trunc(st[j][2], st[j][3]);
    }

#pragma unroll
    for (int j = 0; j < 4; ++j)
#pragma unroll
      for (int r = 0; r < 4; ++r) o[j][r] *= alpha;

    // O^T += V^T P^T : A = Vts rows (dk, kv-contig), B = P^T (lane=q, k=kv)
    const short8 pb0 = *(const short8*)&PT[w][cl * 72 + quad * 8];
    const short8 pb1 = *(const short8*)&PT[w][cl * 72 + 32 + quad * 8];
#pragma unroll
    for (int j = 0; j < 4; ++j) {
      const int row = (j * 16 + cl) * 64;
      const short8 va0 = *(const short8*)&Vts[buf][row + ((quad ^ (cl & 7)) * 8)];
      const short8 va1 = *(const short8*)&Vts[buf][row + (((4 + quad) ^ (cl & 7)) * 8)];
      o[j] = __builtin_amdgcn_mfma_f32_16x16x32_bf16(va0, pb0, o[j], 0, 0, 0);
      o[j] = __builtin_amdgcn_mfma_f32_16x16x32_bf16(va1, pb1, o[j], 0, 0, 0);
    }

    if (segend) {  // normalize + store O (lane owns q-row = qt*64+w*16+cl)
      const float inv = 1.0f / l_i;
      ushort_t* Orow = O + act_base + (size_t)(qt * 64 + w * 16 + cl) * D_ + h * DK_;
#pragma unroll
      for (int j = 0; j < 4; ++j) {
        ushortx4 pk;
#pragma unroll
        for (int r = 0; r < 4; ++r) pk[r] = f2bf(o[j][r] * inv);
        *(ushortx4*)(Orow + j * 16 + quad * 4) = pk;
      }
    }
  }
}

extern "C" void kernel_launch(void* const* d_in, const int* in_sizes, int n_in,
                              void* d_out, int out_size, void* d_ws, size_t ws_size,
                              hipStream_t stream) {
  const float* x  = (const float*)d_in[0];
  const float* Wq = (const float*)d_in[1];
  const float* Wk = (const float*)d_in[2];
  const float* Wv = (const float*)d_in[3];
  const float* Wo = (const float*)d_in[4];
  const float* bq = (const float*)d_in[5];
  const float* bk = (const float*)d_in[6];
  const float* bv = (const float*)d_in[7];
  const float* bo = (const float*)d_in[8];

  const size_t WT_SZ = (size_t)SPLIT_ * D_ * D_;  // 4 Mi elements
  const size_t ACT_SZ = (size_t)B_ * SEQ_ * D_;   // 16 Mi elements

  // ws layout (bf16): xbf[16Mi] | wt[4][4Mi] | Vt[16Mi]  => 96 MiB total
  ushort_t* ws0 = (ushort_t*)d_ws;
  ushort_t* xbf = ws0;
  ushort_t* wtall = xbf + ACT_SZ;
  ushort_t* wtq = wtall;
  ushort_t* wtk = wtq + WT_SZ;
  ushort_t* wtv = wtk + WT_SZ;
  ushort_t* wto = wtv + WT_SZ;
  ushort_t* Vtb = wto + WT_SZ;
  // d_out (16Mi fp32 = 64 MiB) doubles as Q/K bf16 scratch until the final GEMM
  ushort_t* Qb = (ushort_t*)d_out;
  ushort_t* Kb = Qb + ACT_SZ;
  ushort_t* Ob = xbf;  // attention output reuses xbf (x dead after V projection)

  convert_x<<<ACT_SZ / 1024, 256, 0, stream>>>(x, xbf);
  wt_convert_all<<<dim3(32, 32, 16), dim3(32, 8, 1), 0, stream>>>(Wq, Wk, Wv, Wo, wtall);

  dim3 gb(256, 1, 1), gg(8, 8, 16);
  gemm_bt<0><<<gg, gb, 0, stream>>>(xbf, wtq, bq, QSC, Qb);
  gemm_bt<0><<<gg, gb, 0, stream>>>(xbf, wtk, bk, 1.0f, Kb);
  gemm_bt<1><<<gg, gb, 0, stream>>>(xbf, wtv, bv, 1.0f, Vtb);

  dim3 ag(8, 16, 16);
  attn_kernel<<<ag, dim3(256, 1, 1), 0, stream>>>(Qb, Kb, Vtb, Ob);

  gemm_bt<2><<<gg, gb, 0, stream>>>(Ob, wto, bo, 1.0f, d_out);
}

// Round 5
// 470.163 us; speedup vs baseline: 1.4497x; 1.0789x over previous
//
#include <hip/hip_runtime.h>
#include <stdint.h>

#define H_ 16
#define D_ 1024
#define SPLIT_ 4
#define DK_ 64
#define B_ 4
#define SEQ_ 4096
#define L_ 1024

// 0.125 * log2(e): folded into Wq/bq so attn softmax runs in exp2 domain.
#define QSC 0.18033688f

typedef unsigned short ushort_t;
typedef __attribute__((ext_vector_type(8))) short short8;
typedef __attribute__((ext_vector_type(4))) float floatx4;
typedef __attribute__((ext_vector_type(4))) unsigned short ushortx4;

__device__ __forceinline__ ushort_t f2bf(float f) {   // RNE
  union { float f; unsigned u; } cv; cv.f = f;
  unsigned u = cv.u;
  return (ushort_t)((u + 0x7fffu + ((u >> 16) & 1u)) >> 16);
}

// pack two floats -> bf16x2 (truncating) in one v_perm_b32
__device__ __forceinline__ uint32_t pack_bf_trunc(float x, float y) {
#if __has_builtin(__builtin_amdgcn_perm)
  return __builtin_amdgcn_perm(__float_as_uint(y), __float_as_uint(x), 0x07060302u);
#else
  return (__float_as_uint(y) & 0xffff0000u) | (__float_as_uint(x) >> 16);
#endif
}

__device__ __forceinline__ float exp2f_fast(float x) {
#if __has_builtin(__builtin_amdgcn_exp2f)
  return __builtin_amdgcn_exp2f(x);
#else
  return exp2f(x);
#endif
}

// async 16B global->LDS (dest must be wave-uniform base + lane*16)
__device__ __forceinline__ void gl2lds16(const ushort_t* g, ushort_t* l) {
  __builtin_amdgcn_global_load_lds(
      (const __attribute__((address_space(1))) uint32_t*)g,
      (__attribute__((address_space(3))) uint32_t*)l, 16, 0, 0);
}

// ------------- x: fp32 -> bf16 (contiguous) ---------------------------------
__global__ __launch_bounds__(256) void convert_x(const float* __restrict__ X,
                                                 ushort_t* __restrict__ Y) {
  const int i = blockIdx.x * 256 + threadIdx.x;
  const float4 v = ((const float4*)X)[i];
  ushortx4 o;
  o[0] = f2bf(v.x); o[1] = f2bf(v.y); o[2] = f2bf(v.z); o[3] = f2bf(v.w);
  ((ushortx4*)Y)[i] = o;
}

// ------------- all 4 weights: W[s][d][e] fp32 -> Wt[mat][s][e][d] bf16 ------
__global__ __launch_bounds__(256) void wt_convert_all(const float* __restrict__ W0,
                                                      const float* __restrict__ W1,
                                                      const float* __restrict__ W2,
                                                      const float* __restrict__ W3,
                                                      ushort_t* __restrict__ Wt) {
  __shared__ ushort_t tile[32][33];
  const int z = blockIdx.z, mat = z >> 2, s = z & 3;
  const float* W = (mat == 0) ? W0 : (mat == 1) ? W1 : (mat == 2) ? W2 : W3;
  const float scale = (mat == 0) ? QSC : 1.0f;
  const float* Ws = W + (size_t)s * D_ * D_;
  ushort_t* Wts = Wt + ((size_t)mat * SPLIT_ + s) * D_ * D_;
  const int e0 = blockIdx.x * 32, d0 = blockIdx.y * 32;
  for (int i = threadIdx.y; i < 32; i += 8)
    tile[i][threadIdx.x] = f2bf(Ws[(size_t)(d0 + i) * D_ + e0 + threadIdx.x] * scale);
  __syncthreads();
  for (int i = threadIdx.y; i < 32; i += 8)
    Wts[(size_t)(e0 + i) * D_ + d0 + threadIdx.x] = tile[threadIdx.x][i];
}

// ------------- GEMM: C[bs] = X[bs] @ W[s] + bias[s]*bscale  (Wt = W^T) ------
// Grid (8,128): blockIdx.x pins the XCD (round-robin on linear id % 8).
// XCD x handles bs in {x, x+8} (same s -> same weight): per-XCD working set
// ~6 MB (A-slabs + W), L2-resident, vs 32 MB A streamed before.
// 128x128 tile, BK=32, 256 thr (2x2 waves of 64x64), 16x16x32 bf16 MFMA.
// MODE 0: C bf16 [l][e]; MODE 1: Vt bf16 [e][l]; MODE 2: C fp32 [l][e].
template <int MODE>
__global__ __launch_bounds__(256) void gemm_bt(const ushort_t* __restrict__ X,
                                               const ushort_t* __restrict__ Wt,
                                               const float* __restrict__ bias,
                                               float bscale,
                                               void* __restrict__ Cv) {
  __shared__ __attribute__((aligned(16))) ushort_t SH[8192];  // As|Bs, then CT
  ushort_t* As = SH;
  ushort_t* Bs = SH + 4096;

  const int xcd = blockIdx.x;
  const int u = blockIdx.y;
  const int bs = xcd + ((u >> 6) << 3);
  const int mn = u & 63;
  const int m0 = (mn >> 3) * 128;
  const int n0 = (mn & 7) * 128;
  const int s = bs & 3;
  const ushort_t* Xb = X + (size_t)bs * (L_ * D_);
  const ushort_t* Wts = Wt + (size_t)s * (D_ * D_);

  const int t = threadIdx.x;
  const int lane = t & 63;
  const int w = t >> 6;
  const int wm = w >> 1, wn = w & 1;
  const int quad = lane >> 4, cl = lane & 15;

  floatx4 acc[4][4];
  floatx4 zero = {0.f, 0.f, 0.f, 0.f};
#pragma unroll
  for (int i = 0; i < 4; ++i)
#pragma unroll
    for (int j = 0; j < 4; ++j) acc[i][j] = zero;

  const int c0 = t, c1 = t + 256;
  const int r0 = c0 >> 2, cc0 = ((c0 & 3) ^ (r0 & 3)) * 8;
  const int r1 = c1 >> 2, cc1 = ((c1 & 3) ^ (r1 & 3)) * 8;
  const int sw = (quad ^ (cl & 3)) * 8;

  for (int k0 = 0; k0 < D_; k0 += 32) {
    gl2lds16(Xb + (size_t)(m0 + r0) * D_ + k0 + cc0, &As[c0 * 8]);
    gl2lds16(Xb + (size_t)(m0 + r1) * D_ + k0 + cc1, &As[c1 * 8]);
    gl2lds16(Wts + (size_t)(n0 + r0) * D_ + k0 + cc0, &Bs[c0 * 8]);
    gl2lds16(Wts + (size_t)(n0 + r1) * D_ + k0 + cc1, &Bs[c1 * 8]);
    __syncthreads();
    short8 a[4], b[4];
#pragma unroll
    for (int i = 0; i < 4; ++i)
      a[i] = *(const short8*)&As[(wm * 64 + i * 16 + cl) * 32 + sw];
#pragma unroll
    for (int j = 0; j < 4; ++j)
      b[j] = *(const short8*)&Bs[(wn * 64 + j * 16 + cl) * 32 + sw];
#pragma unroll
    for (int i = 0; i < 4; ++i)
#pragma unroll
      for (int j = 0; j < 4; ++j)
        acc[i][j] = __builtin_amdgcn_mfma_f32_16x16x32_bf16(a[i], b[j], acc[i][j], 0, 0, 0);
    __syncthreads();
  }

  // bias per output column (C/D layout: col=lane&15, row=quad*4+reg)
  float bvj[4];
#pragma unroll
  for (int j = 0; j < 4; ++j)
    bvj[j] = bias[s * D_ + n0 + wn * 64 + j * 16 + cl] * bscale;

  if (MODE == 2) {  // direct fp32 stores (64B segments per quad-row)
#pragma unroll
    for (int j = 0; j < 4; ++j) {
      const int col = n0 + wn * 64 + j * 16 + cl;
#pragma unroll
      for (int i = 0; i < 4; ++i) {
        const int rb = m0 + wm * 64 + i * 16 + quad * 4;
        float* Cf = (float*)Cv + (size_t)bs * (L_ * D_) + (size_t)rb * D_ + col;
#pragma unroll
        for (int r = 0; r < 4; ++r) Cf[(size_t)r * D_] = acc[i][j][r] + bvj[j];
      }
    }
    return;
  }

  // LDS-staged coalesced epilogue. CT = 64x128 bf16 tile (16KB), XOR-swizzled
  ushort_t* CT = SH;
#pragma unroll
  for (int ph = 0; ph < 2; ++ph) {
    __syncthreads();
    if (MODE == 0 ? (wm == ph) : (wn == ph)) {
#pragma unroll
      for (int i = 0; i < 4; ++i)
#pragma unroll
        for (int j = 0; j < 4; ++j)
#pragma unroll
          for (int r = 0; r < 4; ++r) {
            int row, col;
            if (MODE == 0) { row = i * 16 + quad * 4 + r; col = wn * 64 + j * 16 + cl; }
            else           { row = j * 16 + cl;           col = wm * 64 + i * 16 + quad * 4 + r; }
            const int ch = col >> 3, off = col & 7;
            CT[row * 128 + ((ch ^ (row & 15)) << 3) + off] = f2bf(acc[i][j][r] + bvj[j]);
          }
    }
    __syncthreads();
#pragma unroll
    for (int pass = 0; pass < 4; ++pass) {
      const int row = pass * 16 + (t >> 4);
      const int ck = t & 15;
      const short8 v = *(const short8*)&CT[row * 128 + ((ck ^ (row & 15)) << 3)];
      if (MODE == 0) {
        *(short8*)((ushort_t*)Cv + (size_t)bs * (L_ * D_) +
                   (size_t)(m0 + ph * 64 + row) * D_ + n0 + ck * 8) = v;
      } else {
        *(short8*)((ushort_t*)Cv + (size_t)bs * (L_ * D_) +
                   (size_t)(n0 + ph * 64 + row) * L_ + m0 + ck * 8) = v;
      }
    }
  }
}

// ------------- attention tile step (per-wave, no barrier) -------------------
__device__ __forceinline__ void attn_step(const ushort_t* __restrict__ Kbuf,
                                          const ushort_t* __restrict__ Vbuf,
                                          ushort_t* __restrict__ PTw,
                                          const short8 qa0, const short8 qa1,
                                          floatx4 (&o)[4], float& m_i, float& l_i,
                                          const bool diag, const int w,
                                          const int quad, const int cl) {
  floatx4 zero = {0.f, 0.f, 0.f, 0.f};
  const int sw0 = (quad ^ (cl & 7)) * 8;
  const int sw1 = ((4 + quad) ^ (cl & 7)) * 8;

  floatx4 st[4];
#pragma unroll
  for (int j = 0; j < 4; ++j) {
    const int row = (j * 16 + cl) * 64;
    const short8 ka0 = *(const short8*)&Kbuf[row + sw0];
    const short8 ka1 = *(const short8*)&Kbuf[row + sw1];
    floatx4 z = zero;
    z = __builtin_amdgcn_mfma_f32_16x16x32_bf16(ka0, qa0, z, 0, 0, 0);
    z = __builtin_amdgcn_mfma_f32_16x16x32_bf16(ka1, qa1, z, 0, 0, 0);
    st[j] = z;
  }

  if (diag) {  // causal mask on diagonal tile (kv_local > q_local)
    const int ql = w * 16 + cl;
#pragma unroll
    for (int j = 0; j < 4; ++j)
#pragma unroll
      for (int r = 0; r < 4; ++r)
        if (j * 16 + quad * 4 + r > ql) st[j][r] = -1e30f;
  }

  // per-lane softmax over 16 kv values + 2 shfls across quads
  float tm = fmaxf(fmaxf(fmaxf(st[0][0], st[0][1]), fmaxf(st[0][2], st[0][3])),
                   fmaxf(fmaxf(st[1][0], st[1][1]), fmaxf(st[1][2], st[1][3])));
  tm = fmaxf(tm, fmaxf(fmaxf(fmaxf(st[2][0], st[2][1]), fmaxf(st[2][2], st[2][3])),
                       fmaxf(fmaxf(st[3][0], st[3][1]), fmaxf(st[3][2], st[3][3]))));
  tm = fmaxf(tm, __shfl_xor(tm, 16, 64));
  tm = fmaxf(tm, __shfl_xor(tm, 32, 64));
  const float mnew = fmaxf(m_i, tm);
  const float alpha = exp2f_fast(m_i - mnew);
  m_i = mnew;

  float tsv = 0.f;
#pragma unroll
  for (int j = 0; j < 4; ++j)
#pragma unroll
    for (int r = 0; r < 4; ++r) {
      st[j][r] = exp2f_fast(st[j][r] - mnew);
      tsv += st[j][r];
    }
  tsv += __shfl_xor(tsv, 16, 64);
  tsv += __shfl_xor(tsv, 32, 64);
  l_i = l_i * alpha + tsv;

  // P^T pairs -> per-wave LDS (b32 writes)
#pragma unroll
  for (int j = 0; j < 4; ++j) {
    const int base = cl * 72 + j * 16 + quad * 4;
    *(uint32_t*)&PTw[base] = pack_bf_trunc(st[j][0], st[j][1]);
    *(uint32_t*)&PTw[base + 2] = pack_bf_trunc(st[j][2], st[j][3]);
  }

#pragma unroll
  for (int j = 0; j < 4; ++j)
#pragma unroll
    for (int r = 0; r < 4; ++r) o[j][r] *= alpha;

  // O^T += V^T P^T
  const short8 pb0 = *(const short8*)&PTw[cl * 72 + quad * 8];
  const short8 pb1 = *(const short8*)&PTw[cl * 72 + 32 + quad * 8];
#pragma unroll
  for (int j = 0; j < 4; ++j) {
    const int row = (j * 16 + cl) * 64;
    const short8 va0 = *(const short8*)&Vbuf[row + sw0];
    const short8 va1 = *(const short8*)&Vbuf[row + sw1];
    o[j] = __builtin_amdgcn_mfma_f32_16x16x32_bf16(va0, pb0, o[j], 0, 0, 0);
    o[j] = __builtin_amdgcn_mfma_f32_16x16x32_bf16(va1, pb1, o[j], 0, 0, 0);
  }
}

__device__ __forceinline__ void attn_store(ushort_t* __restrict__ O, size_t act_base,
                                           int qt, int h, const floatx4 (&o)[4],
                                           float l_i, int w, int quad, int cl) {
  const float inv = 1.0f / l_i;
  ushort_t* Orow = O + act_base + (size_t)(qt * 64 + w * 16 + cl) * D_ + h * DK_;
#pragma unroll
  for (int j = 0; j < 4; ++j) {
    ushortx4 pk;
#pragma unroll
    for (int r = 0; r < 4; ++r) pk[r] = f2bf(o[j][r] * inv);
    *(ushortx4*)(Orow + j * 16 + quad * 4) = pk;
  }
}

// ------------- flash attention (dual-Q shared-KV) ---------------------------
// Block p keeps q-tiles {p, 15-p} both live and streams kv tiles 0..15-p ONCE
// (16-p staging iters instead of 17): K/V fetch and barriers ~halved per unit
// compute. One barrier per kv tile, double-buffered K/V, per-wave PT (A/B).
__global__ __launch_bounds__(256) void attn_kernel(const ushort_t* __restrict__ Q,
                                                   const ushort_t* __restrict__ K,
                                                   const ushort_t* __restrict__ Vt,
                                                   ushort_t* __restrict__ O) {
  __shared__ __attribute__((aligned(16))) ushort_t Ks[2][64 * 64];   // [kv][dk] swz
  __shared__ __attribute__((aligned(16))) ushort_t Vts[2][64 * 64];  // [dk][kv] swz
  __shared__ __attribute__((aligned(16))) ushort_t PT[8][1152];      // per-wave A/B

  const int p = blockIdx.x, h = blockIdx.y, bs = blockIdx.z;
  const int t = threadIdx.x, lane = t & 63, w = t >> 6;
  const int quad = lane >> 4, cl = lane & 15;
  const size_t act_base = (size_t)bs * (L_ * D_);
  const int qtA = p, qtB = 15 - p;
  const int NIT = 16 - p;  // kv tiles 0..15-p

  const int cA = t, cB = t + 256;
  const int rA = cA >> 3, ccA = ((cA & 7) ^ (rA & 7)) * 8;
  const int rB = cB >> 3, ccB = ((cB & 7) ^ (rB & 7)) * 8;

  const ushort_t* pKA = K + act_base + (size_t)rA * D_ + h * DK_ + ccA;
  const ushort_t* pKB = K + act_base + (size_t)rB * D_ + h * DK_ + ccB;
  const ushort_t* pVA = Vt + act_base + (size_t)(h * DK_ + rA) * L_ + ccA;
  const ushort_t* pVB = Vt + act_base + (size_t)(h * DK_ + rB) * L_ + ccB;
  const size_t kstep = (size_t)64 * D_, vstep = 64;

  floatx4 zero = {0.f, 0.f, 0.f, 0.f};

  // Q fragments for both tiles (B-operand: lane=q-row, k contiguous)
  const ushort_t* QpA = Q + act_base + (size_t)(qtA * 64 + w * 16 + cl) * D_ + h * DK_ + quad * 8;
  const ushort_t* QpB = Q + act_base + (size_t)(qtB * 64 + w * 16 + cl) * D_ + h * DK_ + quad * 8;
  const short8 qaA0 = *(const short8*)QpA;
  const short8 qaA1 = *(const short8*)(QpA + 32);
  const short8 qaB0 = *(const short8*)QpB;
  const short8 qaB1 = *(const short8*)(QpB + 32);

  floatx4 oA[4], oB[4];
#pragma unroll
  for (int j = 0; j < 4; ++j) { oA[j] = zero; oB[j] = zero; }
  float mA = -3.0e38f, lA = 0.f, mB = -3.0e38f, lB = 0.f;

  // issue kv=0 into buf 0
  gl2lds16(pKA, &Ks[0][cA * 8]);
  gl2lds16(pKB, &Ks[0][cB * 8]);
  gl2lds16(pVA, &Vts[0][cA * 8]);
  gl2lds16(pVB, &Vts[0][cB * 8]);

  for (int kv = 0; kv < NIT; ++kv) {
    __syncthreads();  // drains buf[kv&1] loads; prior reads of other buf done
    if (kv + 1 < NIT) {
      pKA += kstep; pKB += kstep; pVA += vstep; pVB += vstep;
      const int nb = (kv + 1) & 1;
      gl2lds16(pKA, &Ks[nb][cA * 8]);
      gl2lds16(pKB, &Ks[nb][cB * 8]);
      gl2lds16(pVA, &Vts[nb][cA * 8]);
      gl2lds16(pVB, &Vts[nb][cB * 8]);
    }
    const int buf = kv & 1;

    if (kv <= p) {
      attn_step(Ks[buf], Vts[buf], PT[w], qaA0, qaA1, oA, mA, lA,
                kv == p, w, quad, cl);
      if (kv == p) attn_store(O, act_base, qtA, h, oA, lA, w, quad, cl);
    }
    attn_step(Ks[buf], Vts[buf], PT[w + 4], qaB0, qaB1, oB, mB, lB,
              kv == NIT - 1, w, quad, cl);
  }
  attn_store(O, act_base, qtB, h, oB, lB, w, quad, cl);
}

extern "C" void kernel_launch(void* const* d_in, const int* in_sizes, int n_in,
                              void* d_out, int out_size, void* d_ws, size_t ws_size,
                              hipStream_t stream) {
  const float* x  = (const float*)d_in[0];
  const float* Wq = (const float*)d_in[1];
  const float* Wk = (const float*)d_in[2];
  const float* Wv = (const float*)d_in[3];
  const float* Wo = (const float*)d_in[4];
  const float* bq = (const float*)d_in[5];
  const float* bk = (const float*)d_in[6];
  const float* bv = (const float*)d_in[7];
  const float* bo = (const float*)d_in[8];

  const size_t WT_SZ = (size_t)SPLIT_ * D_ * D_;  // 4 Mi elements
  const size_t ACT_SZ = (size_t)B_ * SEQ_ * D_;   // 16 Mi elements

  // ws layout (bf16): xbf[16Mi] | wt[4][4Mi] | Vt[16Mi]  => 96 MiB total
  ushort_t* ws0 = (ushort_t*)d_ws;
  ushort_t* xbf = ws0;
  ushort_t* wtall = xbf + ACT_SZ;
  ushort_t* wtq = wtall;
  ushort_t* wtk = wtq + WT_SZ;
  ushort_t* wtv = wtk + WT_SZ;
  ushort_t* wto = wtv + WT_SZ;
  ushort_t* Vtb = wto + WT_SZ;
  // d_out (16Mi fp32 = 64 MiB) doubles as Q/K bf16 scratch until the final GEMM
  ushort_t* Qb = (ushort_t*)d_out;
  ushort_t* Kb = Qb + ACT_SZ;
  ushort_t* Ob = xbf;  // attention output reuses xbf (x dead after V projection)

  convert_x<<<ACT_SZ / 1024, 256, 0, stream>>>(x, xbf);
  wt_convert_all<<<dim3(32, 32, 16), dim3(32, 8, 1), 0, stream>>>(Wq, Wk, Wv, Wo, wtall);

  dim3 gb(256, 1, 1), gg(8, 128, 1);
  gemm_bt<0><<<gg, gb, 0, stream>>>(xbf, wtq, bq, QSC, Qb);
  gemm_bt<0><<<gg, gb, 0, stream>>>(xbf, wtk, bk, 1.0f, Kb);
  gemm_bt<1><<<gg, gb, 0, stream>>>(xbf, wtv, bv, 1.0f, Vtb);

  dim3 ag(8, 16, 16);
  attn_kernel<<<ag, dim3(256, 1, 1), 0, stream>>>(Qb, Kb, Vtb, Ob);

  gemm_bt<2><<<gg, gb, 0, stream>>>(Ob, wto, bo, 1.0f, d_out);
}